// Round 6
// baseline (729.118 us; speedup 1.0000x reference)
//
#include <hip/hip_runtime.h>
#include <hip/hip_bf16.h>
#include <math.h>

// ---- static problem config ----
// B=24, H=W=60, DIM=256, NH=8, HD=32, WS=7, SS=3, N=49, HP=WP=63, NW=81
// rows_att = 24*81*49 = 95256 ; rows_mlp = 24*3600 = 86400

typedef _Float16 half8 __attribute__((ext_vector_type(8)));
typedef _Float16 half4_t __attribute__((ext_vector_type(4)));
typedef float f32x4 __attribute__((ext_vector_type(4)));

// async global->LDS, 16B per lane. LDS dest = uniform base + lane*16.
#define GLDS16(gp, lp)                                                    \
  __builtin_amdgcn_global_load_lds(                                      \
      (__attribute__((address_space(1))) const void*)(gp),               \
      (__attribute__((address_space(3))) void*)(lp), 16, 0, 0)

__device__ __forceinline__ float wave_reduce_sum(float v) {
  v += __shfl_xor(v, 1);
  v += __shfl_xor(v, 2);
  v += __shfl_xor(v, 4);
  v += __shfl_xor(v, 8);
  v += __shfl_xor(v, 16);
  v += __shfl_xor(v, 32);
  return v;
}

// ---------------- weight transpose + f16 convert (Bt layout: N x K) -----------
__global__ __launch_bounds__(256) void prep_weights(
    const float* __restrict__ wqkv, const float* __restrict__ wproj,
    const float* __restrict__ wfc1, const float* __restrict__ wfc2,
    _Float16* __restrict__ oqkv, _Float16* __restrict__ oproj,
    _Float16* __restrict__ ofc1, _Float16* __restrict__ ofc2)
{
  int idx = blockIdx.x * 256 + threadIdx.x;
  if (idx < 196608) {                       // w_qkv: 256x768 -> 768x256
    int n = idx / 256, k = idx % 256;
    oqkv[idx] = (_Float16)wqkv[k * 768 + n];
  } else if (idx < 262144) {                // w_proj: 256x256 -> 256x256
    int i = idx - 196608; int n = i / 256, k = i % 256;
    oproj[i] = (_Float16)wproj[k * 256 + n];
  } else if (idx < 524288) {                // w_fc1: 256x1024 -> 1024x256
    int i = idx - 262144; int n = i / 256, k = i % 256;
    ofc1[i] = (_Float16)wfc1[k * 1024 + n];
  } else {                                  // w_fc2: 1024x256 -> 256x1024
    int i = idx - 524288; int n = i / 1024, k = i % 1024;
    ofc2[i] = (_Float16)wfc2[k * 256 + n];
  }
}

// ------- combined rel-bias + shift-mask table: CB[class][head][64][64] f16 ----
// class c: bit1 = (wh==8), bit0 = (ww==8). Pad rows/cols get -60000 (softmax 0).
__global__ __launch_bounds__(256) void prep_cb(
    const float* __restrict__ rbt, _Float16* __restrict__ cbt)
{
  int idx = blockIdx.x * 256 + threadIdx.x;   // 4*8*64*64 = 131072
  int m = idx & 63, n = (idx >> 6) & 63;
  int hc = idx >> 12; int h = hc & 7, c = hc >> 3;
  float v;
  if (n < 49 && m < 49) {
    int i1 = n / 7, j1 = n % 7, i2 = m / 7, j2 = m % 7;
    float bias = rbt[((i1 - i2 + 6) * 13 + (j1 - j2 + 6)) * 8 + h];
    int rh1 = (c & 2) ? (i1 < 4 ? 1 : 2) : 0;
    int rh2 = (c & 2) ? (i2 < 4 ? 1 : 2) : 0;
    int rw1 = (c & 1) ? (j1 < 4 ? 1 : 2) : 0;
    int rw2 = (c & 1) ? (j2 < 4 ? 1 : 2) : 0;
    v = bias + (((rh1 != rh2) || (rw1 != rw2)) ? -100.f : 0.f);
  } else {
    v = -60000.f;
  }
  cbt[idx] = (_Float16)v;
}

// --------- LN1 fused with pad + cyclic shift(-3,-3) + window partition --------
__global__ __launch_bounds__(256) void ln1_window_kernel(
    const float* __restrict__ x, const float* __restrict__ g,
    const float* __restrict__ bta, _Float16* __restrict__ xw,
    int row0, int rows_c)
{
  int lrow = blockIdx.x * 4 + (threadIdx.x >> 6);
  if (lrow >= rows_c) return;               // whole wave exits together
  int row = row0 + lrow;
  int lane = threadIdx.x & 63;
  int bw = row / 49, n = row - bw * 49;
  int b = bw / 81, win = bw - b * 81;
  int wh = win / 9, ww = win - wh * 9;
  int i = n / 7, j = n - i * 7;
  int sh = wh * 7 + i + 3; if (sh >= 63) sh -= 63;
  int sw = ww * 7 + j + 3; if (sw >= 63) sw -= 63;
  bool valid = (sh < 60) && (sw < 60);
  float4 v = make_float4(0.f, 0.f, 0.f, 0.f);
  if (valid)
    v = reinterpret_cast<const float4*>(x + ((size_t)b * 3600 + sh * 60 + sw) * 256)[lane];
  float s = v.x + v.y + v.z + v.w;
  s = wave_reduce_sum(s);
  float mu = s * (1.f / 256.f);
  float dx = v.x - mu, dy = v.y - mu, dz = v.z - mu, dw = v.w - mu;
  float q = dx * dx + dy * dy + dz * dz + dw * dw;
  q = wave_reduce_sum(q);
  float rs = rsqrtf(q * (1.f / 256.f) + 1e-5f);
  float4 gv = reinterpret_cast<const float4*>(g)[lane];
  float4 bv = reinterpret_cast<const float4*>(bta)[lane];
  union { _Float16 h[4]; uint2 u; } pk;
  if (valid) {
    pk.h[0] = (_Float16)(dx * rs * gv.x + bv.x);
    pk.h[1] = (_Float16)(dy * rs * gv.y + bv.y);
    pk.h[2] = (_Float16)(dz * rs * gv.z + bv.z);
    pk.h[3] = (_Float16)(dw * rs * gv.w + bv.w);
  } else {
    pk.h[0] = pk.h[1] = pk.h[2] = pk.h[3] = (_Float16)0.f;
  }
  *reinterpret_cast<uint2*>(xw + (size_t)lrow * 256 + lane * 4) = pk.u;
}

// --------------------------- MFMA f16 GEMM (Bt input) -------------------------
// C[M,N] = A[M,K] * Bt[N,K]^T + bias. 128x128 tile, 4 waves, 4x4 16x16x32
// frags with SWAPPED operands (mfma(b,a)): each lane's f32x4 acc = 4 consecutive
// output columns of one row -> register-direct vectorized epilogue.
// BK=64, double-buffered LDS, global_load_lds width-16 staging.
__global__ __launch_bounds__(256, 2) void gemm_kernel(
    const _Float16* __restrict__ A, const _Float16* __restrict__ Bt,
    const float* __restrict__ bias, const float* __restrict__ resid,
    void* __restrict__ out, int M, int N, int K, int mode, int row0)
{
  __shared__ __align__(16) _Float16 lds[2][2][8192];  // [buf][A/B][128*64]
  const int tid = threadIdx.x;
  const int n0 = blockIdx.x * 128, m0 = blockIdx.y * 128;
  const int wv = tid >> 6, ln = tid & 63;
  const int wm = (wv >> 1) * 64, wn = (wv & 1) * 64;
  const int quad = ln >> 4, l16 = ln & 15;

  const int rl = ln >> 3;                 // row within slot
  const int gseg = ((ln & 7) ^ rl) << 3;  // swizzled 16B segment (f16 units)
  const _Float16* gA[4]; const _Float16* gB[4];
#pragma unroll
  for (int s = 0; s < 4; s++) {
    int r = wv * 32 + s * 8 + rl;
    int gm = m0 + r; if (gm >= M) gm = M - 1;   // clamp: dup rows, epi-skipped
    gA[s] = A + (size_t)gm * K + gseg;
    gB[s] = Bt + (size_t)(n0 + r) * K + gseg;
  }

  int offA[2][4], offB[2][4];
#pragma unroll
  for (int i = 0; i < 4; i++) {
    int ra = wm + i * 16 + l16;
    int rb = wn + i * 16 + l16;
    int sw0 = l16 & 7;
#pragma unroll
    for (int ks = 0; ks < 2; ks++) {
      offA[ks][i] = ra * 64 + (((ks * 4 + quad) ^ sw0) << 3);
      offB[ks][i] = rb * 64 + (((ks * 4 + quad) ^ sw0) << 3);
    }
  }

  f32x4 acc[4][4];
#pragma unroll
  for (int i = 0; i < 4; i++)
#pragma unroll
    for (int j = 0; j < 4; j++) acc[i][j] = (f32x4)0.f;

#define STAGE(buf, koff)                                                   \
  {                                                                        \
    _Float16* la = &lds[buf][0][wv * 2048];                                \
    _Float16* lb = &lds[buf][1][wv * 2048];                                \
    GLDS16(gA[0] + (koff), la);        GLDS16(gB[0] + (koff), lb);         \
    GLDS16(gA[1] + (koff), la + 512);  GLDS16(gB[1] + (koff), lb + 512);   \
    GLDS16(gA[2] + (koff), la + 1024); GLDS16(gB[2] + (koff), lb + 1024);  \
    GLDS16(gA[3] + (koff), la + 1536); GLDS16(gB[3] + (koff), lb + 1536);  \
  }

  const int nt = K >> 6;
  STAGE(0, 0);
  __syncthreads();
  for (int t = 0; t < nt; t++) {
    const int cur = t & 1;
    half8 a0[4], b0[4], a1[4], b1[4];
#pragma unroll
    for (int i = 0; i < 4; i++) {
      a0[i] = *reinterpret_cast<const half8*>(&lds[cur][0][offA[0][i]]);
      a1[i] = *reinterpret_cast<const half8*>(&lds[cur][0][offA[1][i]]);
      b0[i] = *reinterpret_cast<const half8*>(&lds[cur][1][offB[0][i]]);
      b1[i] = *reinterpret_cast<const half8*>(&lds[cur][1][offB[1][i]]);
    }
    if (t + 1 < nt) STAGE(cur ^ 1, (t + 1) << 6);
#pragma unroll
    for (int i = 0; i < 4; i++)
#pragma unroll
      for (int j = 0; j < 4; j++)
        acc[i][j] = __builtin_amdgcn_mfma_f32_16x16x32_f16(b0[j], a0[i], acc[i][j], 0, 0, 0);
#pragma unroll
    for (int i = 0; i < 4; i++)
#pragma unroll
      for (int j = 0; j < 4; j++)
        acc[i][j] = __builtin_amdgcn_mfma_f32_16x16x32_f16(b1[j], a1[i], acc[i][j], 0, 0, 0);
    __syncthreads();
  }
#undef STAGE

  f32x4 bias4[4];
#pragma unroll
  for (int j = 0; j < 4; j++)
    bias4[j] = *reinterpret_cast<const f32x4*>(bias + n0 + wn + j * 16 + quad * 4);

#pragma unroll
  for (int i = 0; i < 4; i++) {
    int gm = m0 + wm + i * 16 + l16;
    if (gm >= M) continue;
    if (mode == 0) {               // qkv: f16 out, scale q columns
      _Float16* op = reinterpret_cast<_Float16*>(out) + (size_t)gm * N + n0 + wn;
#pragma unroll
      for (int j = 0; j < 4; j++) {
        float sc = (n0 + wn + j * 16) < 256 ? 0.17677669529663687f : 1.f;
        half4_t o4;
#pragma unroll
        for (int r = 0; r < 4; r++)
          o4[r] = (_Float16)((acc[i][j][r] + bias4[j][r]) * sc);
        *reinterpret_cast<half4_t*>(op + j * 16 + quad * 4) = o4;
      }
    } else {                       // mode 1: reverse window+shift+unpad+resid
      int gmg = gm + row0;
      int bw = gmg / 49, nn = gmg - bw * 49;
      int bidx = bw / 81, win = bw - bidx * 81;
      int wh = win / 9, wwn = win - wh * 9;
      int ii = nn / 7, jj = nn - ii * 7;
      int sh = wh * 7 + ii + 3; if (sh >= 63) sh -= 63;
      int sw = wwn * 7 + jj + 3; if (sw >= 63) sw -= 63;
      if (sh < 60 && sw < 60) {
        size_t o = ((size_t)bidx * 3600 + sh * 60 + sw) * 256 + n0 + wn;
        float* op = reinterpret_cast<float*>(out) + o;
        const float* rp = resid + o;
#pragma unroll
        for (int j = 0; j < 4; j++) {
          f32x4 rv = *reinterpret_cast<const f32x4*>(rp + j * 16 + quad * 4);
          f32x4 v = acc[i][j] + bias4[j] + rv;
          *reinterpret_cast<f32x4*>(op + j * 16 + quad * 4) = v;
        }
      }
    }
  }
}

// -------------- fused MLP: LN2 + FC1 + GELU + FC2 + residual ------------------
// One block = 32 rows. 4 waves COLUMN-split: wave computes all 32 rows x 1/4 of
// the columns. LDS: A 16KB + H dbuf 2x8KB = 32KB; __launch_bounds__(256,4) ->
// 4 blocks/CU = 16 waves/CU for latency hiding (R5 was 8). One barrier/chunk.
// h never touches HBM; W1/W2 frags direct from global (L2-resident).
__global__ __launch_bounds__(256, 4) void fused_mlp_kernel(
    const float* __restrict__ X, const _Float16* __restrict__ W1t,
    const float* __restrict__ B1v, const _Float16* __restrict__ W2t,
    const float* __restrict__ B2v, const float* __restrict__ g,
    const float* __restrict__ bt, float* __restrict__ out, int M)
{
  __shared__ __align__(16) _Float16 Alds[32 * 256];     // 16 KB
  __shared__ __align__(16) _Float16 Hlds[2][32 * 128];  // 2 x 8 KB
  const int tid = threadIdx.x;
  const int wv = tid >> 6, ln = tid & 63;
  const int quad = ln >> 4, l16 = ln & 15;
  const int m0 = blockIdx.x * 32;
  const int wn1 = wv * 32;     // GEMM1 col base (128-wide chunk)
  const int wn2 = wv * 64;     // GEMM2 col base (256-wide out)

  // ---- LN2: wave wv normalizes rows [wv*8, wv*8+8) into Alds ----
  {
    float4 gv = reinterpret_cast<const float4*>(g)[ln];
    float4 bv = reinterpret_cast<const float4*>(bt)[ln];
    const int seg = ln >> 1;    // 16B segment within row (32/row)
    for (int rr = 0; rr < 8; rr++) {
      int lr = wv * 8 + rr;
      int gr = m0 + lr; if (gr >= M) gr = M - 1;
      float4 v = reinterpret_cast<const float4*>(X + (size_t)gr * 256)[ln];
      float s = wave_reduce_sum(v.x + v.y + v.z + v.w);
      float mu = s * (1.f / 256.f);
      float dx = v.x - mu, dy = v.y - mu, dz = v.z - mu, dw = v.w - mu;
      float q = wave_reduce_sum(dx * dx + dy * dy + dz * dz + dw * dw);
      float rs = rsqrtf(q * (1.f / 256.f) + 1e-5f);
      union { _Float16 h[4]; uint2 u; } pk;
      pk.h[0] = (_Float16)(dx * rs * gv.x + bv.x);
      pk.h[1] = (_Float16)(dy * rs * gv.y + bv.y);
      pk.h[2] = (_Float16)(dz * rs * gv.z + bv.z);
      pk.h[3] = (_Float16)(dw * rs * gv.w + bv.w);
      *reinterpret_cast<uint2*>(
          &Alds[lr * 256 + ((seg ^ (lr & 31)) << 3) + (ln & 1) * 4]) = pk.u;
    }
  }

  // ---- preload acc = X + b_fc2 (residual + bias folded) ----
  f32x4 acc[2][4];
  {
    f32x4 b2q[4];
#pragma unroll
    for (int j = 0; j < 4; j++)
      b2q[j] = *reinterpret_cast<const f32x4*>(B2v + wn2 + j * 16 + quad * 4);
#pragma unroll
    for (int i = 0; i < 2; i++) {
      int gr = m0 + i * 16 + l16; if (gr >= M) gr = M - 1;
      const float* xp = X + (size_t)gr * 256 + wn2;
#pragma unroll
      for (int j = 0; j < 4; j++)
        acc[i][j] = *reinterpret_cast<const f32x4*>(xp + j * 16 + quad * 4) + b2q[j];
    }
  }
  __syncthreads();   // Alds complete

  for (int n1c = 0; n1c < 8; n1c++) {
    // ---- GEMM1: acch[32 x 32(wave)] = A x W1t[chunk]^T ----
    f32x4 acch[2][2];
#pragma unroll
    for (int i = 0; i < 2; i++)
#pragma unroll
      for (int j = 0; j < 2; j++) acch[i][j] = (f32x4)0.f;
    const _Float16* w1p = W1t + (size_t)(n1c * 128 + wn1) * 256;
#pragma unroll
    for (int st = 0; st < 8; st++) {
      half8 bf[2], af[2];
#pragma unroll
      for (int j = 0; j < 2; j++)
        bf[j] = *reinterpret_cast<const half8*>(
            w1p + (size_t)(j * 16 + l16) * 256 + st * 32 + quad * 8);
#pragma unroll
      for (int i = 0; i < 2; i++) {
        int ra = i * 16 + l16;
        af[i] = *reinterpret_cast<const half8*>(
            &Alds[ra * 256 + (((st * 4 + quad) ^ (ra & 31)) << 3)]);
      }
#pragma unroll
      for (int i = 0; i < 2; i++)
#pragma unroll
        for (int j = 0; j < 2; j++)
          acch[i][j] = __builtin_amdgcn_mfma_f32_16x16x32_f16(bf[j], af[i], acch[i][j], 0, 0, 0);
    }
    // ---- bias + GELU -> Hlds[n1c&1] (f16, swizzled) ----
    _Float16* hb = &Hlds[n1c & 1][0];
    {
      f32x4 b1q[2];
#pragma unroll
      for (int j = 0; j < 2; j++)
        b1q[j] = *reinterpret_cast<const f32x4*>(B1v + n1c * 128 + wn1 + j * 16 + quad * 4);
#pragma unroll
      for (int i = 0; i < 2; i++) {
        int m = i * 16 + l16;
#pragma unroll
        for (int j = 0; j < 2; j++) {
          int n = wn1 + j * 16 + quad * 4;
          half4_t o4;
#pragma unroll
          for (int r = 0; r < 4; r++) {
            float v = acch[i][j][r] + b1q[j][r];
            v = 0.5f * v * (1.f + erff(v * 0.70710678118654752f));
            o4[r] = (_Float16)v;
          }
          *reinterpret_cast<half4_t*>(
              &hb[m * 128 + (((n >> 3) ^ (m & 15)) << 3) + (quad & 1) * 4]) = o4;
        }
      }
    }
    __syncthreads();   // Hlds[buf] complete (prev-buf WAR fenced by barrier chain)
    // ---- GEMM2: acc += H x W2t[:, chunk]^T ----
    const _Float16* w2p = W2t + (size_t)wn2 * 1024 + n1c * 128;
#pragma unroll
    for (int p = 0; p < 4; p++) {
      half8 hf[2], b2f[4];
#pragma unroll
      for (int j = 0; j < 4; j++)
        b2f[j] = *reinterpret_cast<const half8*>(
            w2p + (size_t)(j * 16 + l16) * 1024 + p * 32 + quad * 8);
#pragma unroll
      for (int i = 0; i < 2; i++) {
        int mh = i * 16 + l16;
        hf[i] = *reinterpret_cast<const half8*>(
            &hb[mh * 128 + (((p * 4 + quad) ^ (mh & 15)) << 3)]);
      }
#pragma unroll
      for (int i = 0; i < 2; i++)
#pragma unroll
        for (int j = 0; j < 4; j++)
          acc[i][j] = __builtin_amdgcn_mfma_f32_16x16x32_f16(b2f[j], hf[i], acc[i][j], 0, 0, 0);
    }
  }

  // ---- store out (fp32, in-place over X rows) ----
#pragma unroll
  for (int i = 0; i < 2; i++) {
    int gm = m0 + i * 16 + l16;
    if (gm >= M) continue;
    float* op = out + (size_t)gm * 256 + wn2;
#pragma unroll
    for (int j = 0; j < 4; j++)
      *reinterpret_cast<f32x4*>(op + j * 16 + quad * 4) = acc[i][j];
  }
}

// ------------------------ MFMA windowed attention -----------------------------
__global__ __launch_bounds__(64) void attn_mfma(
    const _Float16* __restrict__ qkv, const _Float16* __restrict__ cbt,
    _Float16* __restrict__ outp)
{
  __shared__ __align__(16) _Float16 VT[32][72];   // V^T[d][m], m 49..63 zeroed
  __shared__ __align__(16) _Float16 Ps[64][72];   // P[n][m]
  const int bwh = blockIdx.x;
  const int bw = bwh >> 3, h = bwh & 7;
  const int win = bw % 81;
  const int wh = win / 9, ww = win - wh * 9;
  const int cls = ((wh == 8) ? 2 : 0) | ((ww == 8) ? 1 : 0);
  const int lane = threadIdx.x;
  const int quad = lane >> 4, l16 = lane & 15;

  for (int e = lane; e < 480; e += 64) {          // zero pad cols m=49..63
    int d = e / 15, m = 49 + e % 15;
    VT[d][m] = (_Float16)0.f;
  }
  const size_t vbase = (size_t)bw * 49 * 768 + 512 + h * 32;
  for (int e = lane; e < 1568; e += 64) {
    int m = e >> 5, d = e & 31;
    VT[d][m] = qkv[vbase + (size_t)m * 768 + d];
  }

  const _Float16* qb = qkv + (size_t)bw * 49 * 768 + h * 32 + quad * 8;
  half8 kf[4], qf[4];
  const half8 hz = (half8)(_Float16)0.f;
#pragma unroll
  for (int t = 0; t < 4; t++) {
    int row = t * 16 + l16;
    int rc = row < 49 ? row : 48;
    half8 kv = *reinterpret_cast<const half8*>(qb + 256 + (size_t)rc * 768);
    half8 qv = *reinterpret_cast<const half8*>(qb + (size_t)rc * 768);
    kf[t] = row < 49 ? kv : hz;
    qf[t] = row < 49 ? qv : hz;
  }

  f32x4 S[4][4];
#pragma unroll
  for (int mt = 0; mt < 4; mt++)
#pragma unroll
    for (int nt = 0; nt < 4; nt++) S[mt][nt] = (f32x4)0.f;
#pragma unroll
  for (int mt = 0; mt < 4; mt++)
#pragma unroll
    for (int nt = 0; nt < 4; nt++)
      S[mt][nt] = __builtin_amdgcn_mfma_f32_16x16x32_f16(kf[mt], qf[nt], S[mt][nt], 0, 0, 0);

  const _Float16* cbp = cbt + (((size_t)cls * 8 + h) << 12);
#pragma unroll
  for (int nt = 0; nt < 4; nt++) {
    int n = nt * 16 + l16;
#pragma unroll
    for (int mt = 0; mt < 4; mt++) {
      half4_t cb4 = *reinterpret_cast<const half4_t*>(cbp + n * 64 + mt * 16 + quad * 4);
#pragma unroll
      for (int r = 0; r < 4; r++) S[mt][nt][r] += (float)cb4[r];
    }
  }

  float inv[4];
#pragma unroll
  for (int nt = 0; nt < 4; nt++) {
    float mx = -3.0e38f;
#pragma unroll
    for (int mt = 0; mt < 4; mt++)
#pragma unroll
      for (int r = 0; r < 4; r++) mx = fmaxf(mx, S[mt][nt][r]);
    mx = fmaxf(mx, __shfl_xor(mx, 16));
    mx = fmaxf(mx, __shfl_xor(mx, 32));
    float sm = 0.f;
#pragma unroll
    for (int mt = 0; mt < 4; mt++)
#pragma unroll
      for (int r = 0; r < 4; r++) {
        float e = __expf(S[mt][nt][r] - mx);
        S[mt][nt][r] = e;
        sm += e;
      }
    sm += __shfl_xor(sm, 16);
    sm += __shfl_xor(sm, 32);
    inv[nt] = 1.f / sm;
  }

#pragma unroll
  for (int nt = 0; nt < 4; nt++) {
#pragma unroll
    for (int mt = 0; mt < 4; mt++) {
      half4_t p;
#pragma unroll
      for (int r = 0; r < 4; r++) p[r] = (_Float16)(S[mt][nt][r] * inv[nt]);
      *reinterpret_cast<half4_t*>(&Ps[nt * 16 + l16][mt * 16 + quad * 4]) = p;
    }
  }
  __syncthreads();

  f32x4 O[2][4];
#pragma unroll
  for (int dt = 0; dt < 2; dt++)
#pragma unroll
    for (int nt = 0; nt < 4; nt++) O[dt][nt] = (f32x4)0.f;
#pragma unroll
  for (int ks = 0; ks < 2; ks++) {
    half8 va[2], pb[4];
#pragma unroll
    for (int dt = 0; dt < 2; dt++)
      va[dt] = *reinterpret_cast<const half8*>(&VT[dt * 16 + l16][ks * 32 + quad * 8]);
#pragma unroll
    for (int nt = 0; nt < 4; nt++)
      pb[nt] = *reinterpret_cast<const half8*>(&Ps[nt * 16 + l16][ks * 32 + quad * 8]);
#pragma unroll
    for (int dt = 0; dt < 2; dt++)
#pragma unroll
      for (int nt = 0; nt < 4; nt++)
        O[dt][nt] = __builtin_amdgcn_mfma_f32_16x16x32_f16(va[dt], pb[nt], O[dt][nt], 0, 0, 0);
  }

#pragma unroll
  for (int nt = 0; nt < 4; nt++) {
    int n = nt * 16 + l16;
    if (n < 49) {
#pragma unroll
      for (int dt = 0; dt < 2; dt++) {
        half4_t o4;
#pragma unroll
        for (int r = 0; r < 4; r++) o4[r] = (_Float16)O[dt][nt][r];
        *reinterpret_cast<half4_t*>(
            outp + ((size_t)bw * 49 + n) * 256 + h * 32 + dt * 16 + quad * 4) = o4;
      }
    }
  }
}

// --------------------------------- launcher -----------------------------------
extern "C" void kernel_launch(void* const* d_in, const int* in_sizes, int n_in,
                              void* d_out, int out_size, void* d_ws, size_t ws_size,
                              hipStream_t stream) {
  const float* x      = (const float*)d_in[0];
  const float* g1     = (const float*)d_in[1];
  const float* b1     = (const float*)d_in[2];
  const float* w_qkv  = (const float*)d_in[3];
  const float* b_qkv  = (const float*)d_in[4];
  const float* rbt    = (const float*)d_in[5];
  const float* w_proj = (const float*)d_in[6];
  const float* b_proj = (const float*)d_in[7];
  const float* g2     = (const float*)d_in[8];
  const float* b2     = (const float*)d_in[9];
  const float* w_fc1  = (const float*)d_in[10];
  const float* b_fc1  = (const float*)d_in[11];
  const float* w_fc2  = (const float*)d_in[12];
  const float* b_fc2  = (const float*)d_in[13];
  float* outp = (float*)d_out;   // doubles as the x2 residual buffer

  // weights (persistent): 1.5 MB transposed f16 + 256 KB CB table
  char* ws = (char*)d_ws;
  _Float16* wqkvT  = (_Float16*)(ws + 0);          // 768*256*2  = 393216
  _Float16* wprojT = (_Float16*)(ws + 393216);     // 256*256*2  = 131072
  _Float16* wfc1T  = (_Float16*)(ws + 524288);     // 1024*256*2 = 524288
  _Float16* wfc2T  = (_Float16*)(ws + 1048576);    // 256*1024*2 = 524288
  _Float16* cbt    = (_Float16*)(ws + 1572864);    // 4*8*64*64*2 = 262144
  const size_t WB = 1835008;

  // chunk size: largest cb (batches per chunk) whose scratch fits ws_size.
  // region1 (xw/attn_out): cb*3969*256*2 = cb*2032128
  // region2 (qkv):         cb*3969*768*2 = cb*6096384
  const int cand[8] = {24, 12, 8, 6, 4, 3, 2, 1};
  int cb = 1;
  for (int ci = 0; ci < 8; ci++) {
    size_t need = WB + (size_t)cand[ci] * (2032128u + 6096384u);
    if (ws_size >= need) { cb = cand[ci]; break; }
  }
  const int nch = 24 / cb;

  _Float16* r1 = (_Float16*)(ws + WB);                               // xw / attn_out
  _Float16* r2 = (_Float16*)(ws + WB + (size_t)cb * 2032128u);       // qkv

  prep_weights<<<3072, 256, 0, stream>>>(w_qkv, w_proj, w_fc1, w_fc2,
                                         wqkvT, wprojT, wfc1T, wfc2T);
  prep_cb<<<512, 256, 0, stream>>>(rbt, cbt);

  for (int c = 0; c < nch; c++) {
    const int b0 = c * cb;
    const int rows_att = cb * 81 * 49;      // 3969*cb
    const int row0_att = b0 * 81 * 49;
    const int rows_mlp = cb * 3600;
    const int row0_mlp = b0 * 3600;

    // LN1 + shift + pad + window partition -> r1 (f16)
    ln1_window_kernel<<<(rows_att + 3) / 4, 256, 0, stream>>>(
        x, g1, b1, r1, row0_att, rows_att);
    // QKV GEMM -> r2 (f16), q pre-scaled  (grid: x = n-blocks for L2 A-reuse)
    {
      dim3 g(6, (rows_att + 127) / 128);
      gemm_kernel<<<g, 256, 0, stream>>>(r1, wqkvT, b_qkv, nullptr, r2,
                                         rows_att, 768, 256, 0, 0);
    }
    // MFMA windowed attention -> r1 (f16) (r1's xw is dead)
    attn_mfma<<<cb * 81 * 8, 64, 0, stream>>>(r2, cbt, r1);
    // proj GEMM + reverse-window scatter + residual -> d_out (fp32)
    {
      dim3 g(2, (rows_att + 127) / 128);
      gemm_kernel<<<g, 256, 0, stream>>>(r1, wprojT, b_proj, x, outp,
                                         rows_att, 256, 256, 1, row0_att);
    }
    // fused LN2 + FC1 + GELU + FC2 + residual (in-place on d_out)
    {
      float* od = outp + (size_t)row0_mlp * 256;
      fused_mlp_kernel<<<(rows_mlp + 31) / 32, 256, 0, stream>>>(
          od, wfc1T, b_fc1, wfc2T, b_fc2, g2, b2, od, rows_mlp);
    }
  }
}

// Round 7
// 631.793 us; speedup vs baseline: 1.1540x; 1.1540x over previous
//
#include <hip/hip_runtime.h>
#include <hip/hip_bf16.h>
#include <math.h>

// ---- static problem config ----
// B=24, H=W=60, DIM=256, NH=8, HD=32, WS=7, SS=3, N=49, HP=WP=63, NW=81
// rows_att = 24*81*49 = 95256 ; rows_mlp = 24*3600 = 86400

typedef _Float16 half8 __attribute__((ext_vector_type(8)));
typedef _Float16 half4_t __attribute__((ext_vector_type(4)));
typedef float f32x4 __attribute__((ext_vector_type(4)));

// async global->LDS, 16B per lane. LDS dest = uniform base + lane*16.
#define GLDS16(gp, lp)                                                    \
  __builtin_amdgcn_global_load_lds(                                      \
      (__attribute__((address_space(1))) const void*)(gp),               \
      (__attribute__((address_space(3))) void*)(lp), 16, 0, 0)

__device__ __forceinline__ float wave_reduce_sum(float v) {
  v += __shfl_xor(v, 1);
  v += __shfl_xor(v, 2);
  v += __shfl_xor(v, 4);
  v += __shfl_xor(v, 8);
  v += __shfl_xor(v, 16);
  v += __shfl_xor(v, 32);
  return v;
}

// ---------------- weight transpose + f16 convert (Bt layout: N x K) -----------
__global__ __launch_bounds__(256) void prep_weights(
    const float* __restrict__ wqkv, const float* __restrict__ wproj,
    const float* __restrict__ wfc1, const float* __restrict__ wfc2,
    _Float16* __restrict__ oqkv, _Float16* __restrict__ oproj,
    _Float16* __restrict__ ofc1, _Float16* __restrict__ ofc2)
{
  int idx = blockIdx.x * 256 + threadIdx.x;
  if (idx < 196608) {                       // w_qkv: 256x768 -> 768x256
    int n = idx / 256, k = idx % 256;
    oqkv[idx] = (_Float16)wqkv[k * 768 + n];
  } else if (idx < 262144) {                // w_proj: 256x256 -> 256x256
    int i = idx - 196608; int n = i / 256, k = i % 256;
    oproj[i] = (_Float16)wproj[k * 256 + n];
  } else if (idx < 524288) {                // w_fc1: 256x1024 -> 1024x256
    int i = idx - 262144; int n = i / 256, k = i % 256;
    ofc1[i] = (_Float16)wfc1[k * 1024 + n];
  } else {                                  // w_fc2: 1024x256 -> 256x1024
    int i = idx - 524288; int n = i / 1024, k = i % 1024;
    ofc2[i] = (_Float16)wfc2[k * 256 + n];
  }
}

// ------- combined rel-bias + shift-mask table: CB[class][head][64][64] f16 ----
// class c: bit1 = (wh==8), bit0 = (ww==8). Pad rows/cols get -60000 (softmax 0).
__global__ __launch_bounds__(256) void prep_cb(
    const float* __restrict__ rbt, _Float16* __restrict__ cbt)
{
  int idx = blockIdx.x * 256 + threadIdx.x;   // 4*8*64*64 = 131072
  int m = idx & 63, n = (idx >> 6) & 63;
  int hc = idx >> 12; int h = hc & 7, c = hc >> 3;
  float v;
  if (n < 49 && m < 49) {
    int i1 = n / 7, j1 = n % 7, i2 = m / 7, j2 = m % 7;
    float bias = rbt[((i1 - i2 + 6) * 13 + (j1 - j2 + 6)) * 8 + h];
    int rh1 = (c & 2) ? (i1 < 4 ? 1 : 2) : 0;
    int rh2 = (c & 2) ? (i2 < 4 ? 1 : 2) : 0;
    int rw1 = (c & 1) ? (j1 < 4 ? 1 : 2) : 0;
    int rw2 = (c & 1) ? (j2 < 4 ? 1 : 2) : 0;
    v = bias + (((rh1 != rh2) || (rw1 != rw2)) ? -100.f : 0.f);
  } else {
    v = -60000.f;
  }
  cbt[idx] = (_Float16)v;
}

// --------- LN1 fused with pad + cyclic shift(-3,-3) + window partition --------
__global__ __launch_bounds__(256) void ln1_window_kernel(
    const float* __restrict__ x, const float* __restrict__ g,
    const float* __restrict__ bta, _Float16* __restrict__ xw,
    int row0, int rows_c)
{
  int lrow = blockIdx.x * 4 + (threadIdx.x >> 6);
  if (lrow >= rows_c) return;               // whole wave exits together
  int row = row0 + lrow;
  int lane = threadIdx.x & 63;
  int bw = row / 49, n = row - bw * 49;
  int b = bw / 81, win = bw - b * 81;
  int wh = win / 9, ww = win - wh * 9;
  int i = n / 7, j = n - i * 7;
  int sh = wh * 7 + i + 3; if (sh >= 63) sh -= 63;
  int sw = ww * 7 + j + 3; if (sw >= 63) sw -= 63;
  bool valid = (sh < 60) && (sw < 60);
  float4 v = make_float4(0.f, 0.f, 0.f, 0.f);
  if (valid)
    v = reinterpret_cast<const float4*>(x + ((size_t)b * 3600 + sh * 60 + sw) * 256)[lane];
  float s = v.x + v.y + v.z + v.w;
  s = wave_reduce_sum(s);
  float mu = s * (1.f / 256.f);
  float dx = v.x - mu, dy = v.y - mu, dz = v.z - mu, dw = v.w - mu;
  float q = dx * dx + dy * dy + dz * dz + dw * dw;
  q = wave_reduce_sum(q);
  float rs = rsqrtf(q * (1.f / 256.f) + 1e-5f);
  float4 gv = reinterpret_cast<const float4*>(g)[lane];
  float4 bv = reinterpret_cast<const float4*>(bta)[lane];
  union { _Float16 h[4]; uint2 u; } pk;
  if (valid) {
    pk.h[0] = (_Float16)(dx * rs * gv.x + bv.x);
    pk.h[1] = (_Float16)(dy * rs * gv.y + bv.y);
    pk.h[2] = (_Float16)(dz * rs * gv.z + bv.z);
    pk.h[3] = (_Float16)(dw * rs * gv.w + bv.w);
  } else {
    pk.h[0] = pk.h[1] = pk.h[2] = pk.h[3] = (_Float16)0.f;
  }
  *reinterpret_cast<uint2*>(xw + (size_t)lrow * 256 + lane * 4) = pk.u;
}

// --------------------------- MFMA f16 GEMM (Bt input) -------------------------
// C[M,N] = A[M,K] * Bt[N,K]^T + bias. 128x128 tile, 4 waves, 4x4 16x16x32
// frags with SWAPPED operands (mfma(b,a)): each lane's f32x4 acc = 4 consecutive
// output columns of one row -> register-direct vectorized epilogue.
// BK=64, double-buffered LDS, global_load_lds width-16 staging.
__global__ __launch_bounds__(256, 2) void gemm_kernel(
    const _Float16* __restrict__ A, const _Float16* __restrict__ Bt,
    const float* __restrict__ bias, const float* __restrict__ resid,
    void* __restrict__ out, int M, int N, int K, int mode, int row0)
{
  __shared__ __align__(16) _Float16 lds[2][2][8192];  // [buf][A/B][128*64]
  const int tid = threadIdx.x;
  const int n0 = blockIdx.x * 128, m0 = blockIdx.y * 128;
  const int wv = tid >> 6, ln = tid & 63;
  const int wm = (wv >> 1) * 64, wn = (wv & 1) * 64;
  const int quad = ln >> 4, l16 = ln & 15;

  const int rl = ln >> 3;                 // row within slot
  const int gseg = ((ln & 7) ^ rl) << 3;  // swizzled 16B segment (f16 units)
  const _Float16* gA[4]; const _Float16* gB[4];
#pragma unroll
  for (int s = 0; s < 4; s++) {
    int r = wv * 32 + s * 8 + rl;
    int gm = m0 + r; if (gm >= M) gm = M - 1;   // clamp: dup rows, epi-skipped
    gA[s] = A + (size_t)gm * K + gseg;
    gB[s] = Bt + (size_t)(n0 + r) * K + gseg;
  }

  int offA[2][4], offB[2][4];
#pragma unroll
  for (int i = 0; i < 4; i++) {
    int ra = wm + i * 16 + l16;
    int rb = wn + i * 16 + l16;
    int sw0 = l16 & 7;
#pragma unroll
    for (int ks = 0; ks < 2; ks++) {
      offA[ks][i] = ra * 64 + (((ks * 4 + quad) ^ sw0) << 3);
      offB[ks][i] = rb * 64 + (((ks * 4 + quad) ^ sw0) << 3);
    }
  }

  f32x4 acc[4][4];
#pragma unroll
  for (int i = 0; i < 4; i++)
#pragma unroll
    for (int j = 0; j < 4; j++) acc[i][j] = (f32x4)0.f;

#define STAGE(buf, koff)                                                   \
  {                                                                        \
    _Float16* la = &lds[buf][0][wv * 2048];                                \
    _Float16* lb = &lds[buf][1][wv * 2048];                                \
    GLDS16(gA[0] + (koff), la);        GLDS16(gB[0] + (koff), lb);         \
    GLDS16(gA[1] + (koff), la + 512);  GLDS16(gB[1] + (koff), lb + 512);   \
    GLDS16(gA[2] + (koff), la + 1024); GLDS16(gB[2] + (koff), lb + 1024);  \
    GLDS16(gA[3] + (koff), la + 1536); GLDS16(gB[3] + (koff), lb + 1536);  \
  }

  const int nt = K >> 6;
  STAGE(0, 0);
  __syncthreads();
  for (int t = 0; t < nt; t++) {
    const int cur = t & 1;
    half8 a0[4], b0[4], a1[4], b1[4];
#pragma unroll
    for (int i = 0; i < 4; i++) {
      a0[i] = *reinterpret_cast<const half8*>(&lds[cur][0][offA[0][i]]);
      a1[i] = *reinterpret_cast<const half8*>(&lds[cur][0][offA[1][i]]);
      b0[i] = *reinterpret_cast<const half8*>(&lds[cur][1][offB[0][i]]);
      b1[i] = *reinterpret_cast<const half8*>(&lds[cur][1][offB[1][i]]);
    }
    if (t + 1 < nt) STAGE(cur ^ 1, (t + 1) << 6);
#pragma unroll
    for (int i = 0; i < 4; i++)
#pragma unroll
      for (int j = 0; j < 4; j++)
        acc[i][j] = __builtin_amdgcn_mfma_f32_16x16x32_f16(b0[j], a0[i], acc[i][j], 0, 0, 0);
#pragma unroll
    for (int i = 0; i < 4; i++)
#pragma unroll
      for (int j = 0; j < 4; j++)
        acc[i][j] = __builtin_amdgcn_mfma_f32_16x16x32_f16(b1[j], a1[i], acc[i][j], 0, 0, 0);
    __syncthreads();
  }
#undef STAGE

  f32x4 bias4[4];
#pragma unroll
  for (int j = 0; j < 4; j++)
    bias4[j] = *reinterpret_cast<const f32x4*>(bias + n0 + wn + j * 16 + quad * 4);

#pragma unroll
  for (int i = 0; i < 4; i++) {
    int gm = m0 + wm + i * 16 + l16;
    if (gm >= M) continue;
    if (mode == 0) {               // qkv: f16 out, scale q columns
      _Float16* op = reinterpret_cast<_Float16*>(out) + (size_t)gm * N + n0 + wn;
#pragma unroll
      for (int j = 0; j < 4; j++) {
        float sc = (n0 + wn + j * 16) < 256 ? 0.17677669529663687f : 1.f;
        half4_t o4;
#pragma unroll
        for (int r = 0; r < 4; r++)
          o4[r] = (_Float16)((acc[i][j][r] + bias4[j][r]) * sc);
        *reinterpret_cast<half4_t*>(op + j * 16 + quad * 4) = o4;
      }
    } else {                       // mode 1: reverse window+shift+unpad+resid
      int gmg = gm + row0;
      int bw = gmg / 49, nn = gmg - bw * 49;
      int bidx = bw / 81, win = bw - bidx * 81;
      int wh = win / 9, wwn = win - wh * 9;
      int ii = nn / 7, jj = nn - ii * 7;
      int sh = wh * 7 + ii + 3; if (sh >= 63) sh -= 63;
      int sw = wwn * 7 + jj + 3; if (sw >= 63) sw -= 63;
      if (sh < 60 && sw < 60) {
        size_t o = ((size_t)bidx * 3600 + sh * 60 + sw) * 256 + n0 + wn;
        float* op = reinterpret_cast<float*>(out) + o;
        const float* rp = resid + o;
#pragma unroll
        for (int j = 0; j < 4; j++) {
          f32x4 rv = *reinterpret_cast<const f32x4*>(rp + j * 16 + quad * 4);
          f32x4 v = acc[i][j] + bias4[j] + rv;
          *reinterpret_cast<f32x4*>(op + j * 16 + quad * 4) = v;
        }
      }
    }
  }
}

// -------------- fused MLP: LN2 + FC1 + GELU + FC2 + residual ------------------
// One block = 64 rows (R5 geometry: best W-load amortization). 4 waves
// COLUMN-split. Key fix vs R5/R6: W1/W2 fragments for the WHOLE chunk are
// batch-loaded into register arrays (16 loads in flight -> one batched L2
// latency per phase instead of 16 serialized dependency stalls). W2 batch
// issues right after GEMM1 so its latency hides under GELU+barrier.
// LDS: A 32KB + H dbuf 2x16KB = 64KB -> 2 blocks/CU; bounds(256,2) -> 256 VGPR.
__global__ __launch_bounds__(256, 2) void fused_mlp_kernel(
    const float* __restrict__ X, const _Float16* __restrict__ W1t,
    const float* __restrict__ B1v, const _Float16* __restrict__ W2t,
    const float* __restrict__ B2v, const float* __restrict__ g,
    const float* __restrict__ bt, float* __restrict__ out, int M)
{
  __shared__ __align__(16) _Float16 Alds[64 * 256];     // 32 KB
  __shared__ __align__(16) _Float16 Hlds[2][64 * 128];  // 2 x 16 KB
  const int tid = threadIdx.x;
  const int wv = tid >> 6, ln = tid & 63;
  const int quad = ln >> 4, l16 = ln & 15;
  const int m0 = blockIdx.x * 64;
  const int wn1 = wv * 32;     // GEMM1 col base (128-wide chunk)
  const int wn2 = wv * 64;     // GEMM2 col base (256-wide out)

  // ---- LN2: wave wv normalizes rows [wv*16, wv*16+16) into Alds ----
  {
    float4 gv = reinterpret_cast<const float4*>(g)[ln];
    float4 bv = reinterpret_cast<const float4*>(bt)[ln];
    const int seg = ln >> 1;    // 16B segment within row (32/row)
    for (int rr = 0; rr < 16; rr++) {
      int lr = wv * 16 + rr;
      int gr = m0 + lr; if (gr >= M) gr = M - 1;
      float4 v = reinterpret_cast<const float4*>(X + (size_t)gr * 256)[ln];
      float s = wave_reduce_sum(v.x + v.y + v.z + v.w);
      float mu = s * (1.f / 256.f);
      float dx = v.x - mu, dy = v.y - mu, dz = v.z - mu, dw = v.w - mu;
      float q = wave_reduce_sum(dx * dx + dy * dy + dz * dz + dw * dw);
      float rs = rsqrtf(q * (1.f / 256.f) + 1e-5f);
      union { _Float16 h[4]; uint2 u; } pk;
      pk.h[0] = (_Float16)(dx * rs * gv.x + bv.x);
      pk.h[1] = (_Float16)(dy * rs * gv.y + bv.y);
      pk.h[2] = (_Float16)(dz * rs * gv.z + bv.z);
      pk.h[3] = (_Float16)(dw * rs * gv.w + bv.w);
      *reinterpret_cast<uint2*>(
          &Alds[lr * 256 + ((seg ^ (lr & 31)) << 3) + (ln & 1) * 4]) = pk.u;
    }
  }

  // ---- preload acc = X + b_fc2 (residual + bias folded) ----
  f32x4 acc[4][4];
  {
    f32x4 b2q[4];
#pragma unroll
    for (int j = 0; j < 4; j++)
      b2q[j] = *reinterpret_cast<const f32x4*>(B2v + wn2 + j * 16 + quad * 4);
#pragma unroll
    for (int i = 0; i < 4; i++) {
      int gr = m0 + i * 16 + l16; if (gr >= M) gr = M - 1;
      const float* xp = X + (size_t)gr * 256 + wn2;
#pragma unroll
      for (int j = 0; j < 4; j++)
        acc[i][j] = *reinterpret_cast<const f32x4*>(xp + j * 16 + quad * 4) + b2q[j];
    }
  }
  __syncthreads();   // Alds complete

  for (int n1c = 0; n1c < 8; n1c++) {
    // ---- batch-load ALL W1 fragments for this chunk (16 loads in flight) ----
    const _Float16* w1p = W1t + (size_t)(n1c * 128 + wn1) * 256;
    half8 w1f[8][2];
#pragma unroll
    for (int st = 0; st < 8; st++)
#pragma unroll
      for (int j = 0; j < 2; j++)
        w1f[st][j] = *reinterpret_cast<const half8*>(
            w1p + (size_t)(j * 16 + l16) * 256 + st * 32 + quad * 8);

    // ---- GEMM1: acch[64 x 32(wave)] = A x W1t[chunk]^T ----
    f32x4 acch[4][2];
#pragma unroll
    for (int i = 0; i < 4; i++)
#pragma unroll
      for (int j = 0; j < 2; j++) acch[i][j] = (f32x4)0.f;
#pragma unroll
    for (int st = 0; st < 8; st++) {
      half8 af[4];
#pragma unroll
      for (int i = 0; i < 4; i++) {
        int ra = i * 16 + l16;
        af[i] = *reinterpret_cast<const half8*>(
            &Alds[ra * 256 + (((st * 4 + quad) ^ (ra & 31)) << 3)]);
      }
#pragma unroll
      for (int i = 0; i < 4; i++)
#pragma unroll
        for (int j = 0; j < 2; j++)
          acch[i][j] = __builtin_amdgcn_mfma_f32_16x16x32_f16(w1f[st][j], af[i], acch[i][j], 0, 0, 0);
    }

    // ---- batch-issue ALL W2 fragments now: latency hides under GELU+barrier --
    const _Float16* w2p = W2t + (size_t)wn2 * 1024 + n1c * 128;
    half8 w2f[4][4];
#pragma unroll
    for (int p = 0; p < 4; p++)
#pragma unroll
      for (int j = 0; j < 4; j++)
        w2f[p][j] = *reinterpret_cast<const half8*>(
            w2p + (size_t)(j * 16 + l16) * 1024 + p * 32 + quad * 8);

    // ---- bias + GELU -> Hlds[n1c&1] (f16, swizzled) ----
    _Float16* hb = &Hlds[n1c & 1][0];
    {
      f32x4 b1q[2];
#pragma unroll
      for (int j = 0; j < 2; j++)
        b1q[j] = *reinterpret_cast<const f32x4*>(B1v + n1c * 128 + wn1 + j * 16 + quad * 4);
#pragma unroll
      for (int i = 0; i < 4; i++) {
        int m = i * 16 + l16;
#pragma unroll
        for (int j = 0; j < 2; j++) {
          int n = wn1 + j * 16 + quad * 4;
          half4_t o4;
#pragma unroll
          for (int r = 0; r < 4; r++) {
            float v = acch[i][j][r] + b1q[j][r];
            v = 0.5f * v * (1.f + erff(v * 0.70710678118654752f));
            o4[r] = (_Float16)v;
          }
          *reinterpret_cast<half4_t*>(
              &hb[m * 128 + (((n >> 3) ^ (m & 15)) << 3) + (quad & 1) * 4]) = o4;
        }
      }
    }
    __syncthreads();   // Hlds[buf] complete (prev-buf WAR fenced by barrier chain)

    // ---- GEMM2: acc += H x W2t[:, chunk]^T (w2f already resident) ----
#pragma unroll
    for (int p = 0; p < 4; p++) {
      half8 hf[4];
#pragma unroll
      for (int i = 0; i < 4; i++) {
        int mh = i * 16 + l16;
        hf[i] = *reinterpret_cast<const half8*>(
            &hb[mh * 128 + (((p * 4 + quad) ^ (mh & 15)) << 3)]);
      }
#pragma unroll
      for (int i = 0; i < 4; i++)
#pragma unroll
        for (int j = 0; j < 4; j++)
          acc[i][j] = __builtin_amdgcn_mfma_f32_16x16x32_f16(w2f[p][j], hf[i], acc[i][j], 0, 0, 0);
    }
  }

  // ---- store out (fp32, in-place over X rows) ----
#pragma unroll
  for (int i = 0; i < 4; i++) {
    int gm = m0 + i * 16 + l16;
    if (gm >= M) continue;
    float* op = out + (size_t)gm * 256 + wn2;
#pragma unroll
    for (int j = 0; j < 4; j++)
      *reinterpret_cast<f32x4*>(op + j * 16 + quad * 4) = acc[i][j];
  }
}

// ------------------------ MFMA windowed attention -----------------------------
__global__ __launch_bounds__(64) void attn_mfma(
    const _Float16* __restrict__ qkv, const _Float16* __restrict__ cbt,
    _Float16* __restrict__ outp)
{
  __shared__ __align__(16) _Float16 VT[32][72];   // V^T[d][m], m 49..63 zeroed
  __shared__ __align__(16) _Float16 Ps[64][72];   // P[n][m]
  const int bwh = blockIdx.x;
  const int bw = bwh >> 3, h = bwh & 7;
  const int win = bw % 81;
  const int wh = win / 9, ww = win - wh * 9;
  const int cls = ((wh == 8) ? 2 : 0) | ((ww == 8) ? 1 : 0);
  const int lane = threadIdx.x;
  const int quad = lane >> 4, l16 = lane & 15;

  for (int e = lane; e < 480; e += 64) {          // zero pad cols m=49..63
    int d = e / 15, m = 49 + e % 15;
    VT[d][m] = (_Float16)0.f;
  }
  const size_t vbase = (size_t)bw * 49 * 768 + 512 + h * 32;
  for (int e = lane; e < 1568; e += 64) {
    int m = e >> 5, d = e & 31;
    VT[d][m] = qkv[vbase + (size_t)m * 768 + d];
  }

  const _Float16* qb = qkv + (size_t)bw * 49 * 768 + h * 32 + quad * 8;
  half8 kf[4], qf[4];
  const half8 hz = (half8)(_Float16)0.f;
#pragma unroll
  for (int t = 0; t < 4; t++) {
    int row = t * 16 + l16;
    int rc = row < 49 ? row : 48;
    half8 kv = *reinterpret_cast<const half8*>(qb + 256 + (size_t)rc * 768);
    half8 qv = *reinterpret_cast<const half8*>(qb + (size_t)rc * 768);
    kf[t] = row < 49 ? kv : hz;
    qf[t] = row < 49 ? qv : hz;
  }

  f32x4 S[4][4];
#pragma unroll
  for (int mt = 0; mt < 4; mt++)
#pragma unroll
    for (int nt = 0; nt < 4; nt++) S[mt][nt] = (f32x4)0.f;
#pragma unroll
  for (int mt = 0; mt < 4; mt++)
#pragma unroll
    for (int nt = 0; nt < 4; nt++)
      S[mt][nt] = __builtin_amdgcn_mfma_f32_16x16x32_f16(kf[mt], qf[nt], S[mt][nt], 0, 0, 0);

  const _Float16* cbp = cbt + (((size_t)cls * 8 + h) << 12);
#pragma unroll
  for (int nt = 0; nt < 4; nt++) {
    int n = nt * 16 + l16;
#pragma unroll
    for (int mt = 0; mt < 4; mt++) {
      half4_t cb4 = *reinterpret_cast<const half4_t*>(cbp + n * 64 + mt * 16 + quad * 4);
#pragma unroll
      for (int r = 0; r < 4; r++) S[mt][nt][r] += (float)cb4[r];
    }
  }

  float inv[4];
#pragma unroll
  for (int nt = 0; nt < 4; nt++) {
    float mx = -3.0e38f;
#pragma unroll
    for (int mt = 0; mt < 4; mt++)
#pragma unroll
      for (int r = 0; r < 4; r++) mx = fmaxf(mx, S[mt][nt][r]);
    mx = fmaxf(mx, __shfl_xor(mx, 16));
    mx = fmaxf(mx, __shfl_xor(mx, 32));
    float sm = 0.f;
#pragma unroll
    for (int mt = 0; mt < 4; mt++)
#pragma unroll
      for (int r = 0; r < 4; r++) {
        float e = __expf(S[mt][nt][r] - mx);
        S[mt][nt][r] = e;
        sm += e;
      }
    sm += __shfl_xor(sm, 16);
    sm += __shfl_xor(sm, 32);
    inv[nt] = 1.f / sm;
  }

#pragma unroll
  for (int nt = 0; nt < 4; nt++) {
#pragma unroll
    for (int mt = 0; mt < 4; mt++) {
      half4_t p;
#pragma unroll
      for (int r = 0; r < 4; r++) p[r] = (_Float16)(S[mt][nt][r] * inv[nt]);
      *reinterpret_cast<half4_t*>(&Ps[nt * 16 + l16][mt * 16 + quad * 4]) = p;
    }
  }
  __syncthreads();

  f32x4 O[2][4];
#pragma unroll
  for (int dt = 0; dt < 2; dt++)
#pragma unroll
    for (int nt = 0; nt < 4; nt++) O[dt][nt] = (f32x4)0.f;
#pragma unroll
  for (int ks = 0; ks < 2; ks++) {
    half8 va[2], pb[4];
#pragma unroll
    for (int dt = 0; dt < 2; dt++)
      va[dt] = *reinterpret_cast<const half8*>(&VT[dt * 16 + l16][ks * 32 + quad * 8]);
#pragma unroll
    for (int nt = 0; nt < 4; nt++)
      pb[nt] = *reinterpret_cast<const half8*>(&Ps[nt * 16 + l16][ks * 32 + quad * 8]);
#pragma unroll
    for (int dt = 0; dt < 2; dt++)
#pragma unroll
      for (int nt = 0; nt < 4; nt++)
        O[dt][nt] = __builtin_amdgcn_mfma_f32_16x16x32_f16(va[dt], pb[nt], O[dt][nt], 0, 0, 0);
  }

#pragma unroll
  for (int nt = 0; nt < 4; nt++) {
    int n = nt * 16 + l16;
    if (n < 49) {
#pragma unroll
      for (int dt = 0; dt < 2; dt++) {
        half4_t o4;
#pragma unroll
        for (int r = 0; r < 4; r++) o4[r] = (_Float16)O[dt][nt][r];
        *reinterpret_cast<half4_t*>(
            outp + ((size_t)bw * 49 + n) * 256 + h * 32 + dt * 16 + quad * 4) = o4;
      }
    }
  }
}

// --------------------------------- launcher -----------------------------------
extern "C" void kernel_launch(void* const* d_in, const int* in_sizes, int n_in,
                              void* d_out, int out_size, void* d_ws, size_t ws_size,
                              hipStream_t stream) {
  const float* x      = (const float*)d_in[0];
  const float* g1     = (const float*)d_in[1];
  const float* b1     = (const float*)d_in[2];
  const float* w_qkv  = (const float*)d_in[3];
  const float* b_qkv  = (const float*)d_in[4];
  const float* rbt    = (const float*)d_in[5];
  const float* w_proj = (const float*)d_in[6];
  const float* b_proj = (const float*)d_in[7];
  const float* g2     = (const float*)d_in[8];
  const float* b2     = (const float*)d_in[9];
  const float* w_fc1  = (const float*)d_in[10];
  const float* b_fc1  = (const float*)d_in[11];
  const float* w_fc2  = (const float*)d_in[12];
  const float* b_fc2  = (const float*)d_in[13];
  float* outp = (float*)d_out;   // doubles as the x2 residual buffer

  // weights (persistent): 1.5 MB transposed f16 + 256 KB CB table
  char* ws = (char*)d_ws;
  _Float16* wqkvT  = (_Float16*)(ws + 0);          // 768*256*2  = 393216
  _Float16* wprojT = (_Float16*)(ws + 393216);     // 256*256*2  = 131072
  _Float16* wfc1T  = (_Float16*)(ws + 524288);     // 1024*256*2 = 524288
  _Float16* wfc2T  = (_Float16*)(ws + 1048576);    // 256*1024*2 = 524288
  _Float16* cbt    = (_Float16*)(ws + 1572864);    // 4*8*64*64*2 = 262144
  const size_t WB = 1835008;

  // chunk size: largest cb (batches per chunk) whose scratch fits ws_size.
  // region1 (xw/attn_out): cb*3969*256*2 = cb*2032128
  // region2 (qkv):         cb*3969*768*2 = cb*6096384
  const int cand[8] = {24, 12, 8, 6, 4, 3, 2, 1};
  int cb = 1;
  for (int ci = 0; ci < 8; ci++) {
    size_t need = WB + (size_t)cand[ci] * (2032128u + 6096384u);
    if (ws_size >= need) { cb = cand[ci]; break; }
  }
  const int nch = 24 / cb;

  _Float16* r1 = (_Float16*)(ws + WB);                               // xw / attn_out
  _Float16* r2 = (_Float16*)(ws + WB + (size_t)cb * 2032128u);       // qkv

  prep_weights<<<3072, 256, 0, stream>>>(w_qkv, w_proj, w_fc1, w_fc2,
                                         wqkvT, wprojT, wfc1T, wfc2T);
  prep_cb<<<512, 256, 0, stream>>>(rbt, cbt);

  for (int c = 0; c < nch; c++) {
    const int b0 = c * cb;
    const int rows_att = cb * 81 * 49;      // 3969*cb
    const int row0_att = b0 * 81 * 49;
    const int rows_mlp = cb * 3600;
    const int row0_mlp = b0 * 3600;

    // LN1 + shift + pad + window partition -> r1 (f16)
    ln1_window_kernel<<<(rows_att + 3) / 4, 256, 0, stream>>>(
        x, g1, b1, r1, row0_att, rows_att);
    // QKV GEMM -> r2 (f16), q pre-scaled  (grid: x = n-blocks for L2 A-reuse)
    {
      dim3 g(6, (rows_att + 127) / 128);
      gemm_kernel<<<g, 256, 0, stream>>>(r1, wqkvT, b_qkv, nullptr, r2,
                                         rows_att, 768, 256, 0, 0);
    }
    // MFMA windowed attention -> r1 (f16) (r1's xw is dead)
    attn_mfma<<<cb * 81 * 8, 64, 0, stream>>>(r2, cbt, r1);
    // proj GEMM + reverse-window scatter + residual -> d_out (fp32)
    {
      dim3 g(2, (rows_att + 127) / 128);
      gemm_kernel<<<g, 256, 0, stream>>>(r1, wprojT, b_proj, x, outp,
                                         rows_att, 256, 256, 1, row0_att);
    }
    // fused LN2 + FC1 + GELU + FC2 + residual (in-place on d_out)
    {
      float* od = outp + (size_t)row0_mlp * 256;
      fused_mlp_kernel<<<(rows_mlp + 63) / 64, 256, 0, stream>>>(
          od, wfc1T, b_fc1, wfc2T, b_fc2, g2, b2, od, rows_mlp);
    }
  }
}

// Round 8
// 616.396 us; speedup vs baseline: 1.1829x; 1.0250x over previous
//
#include <hip/hip_runtime.h>
#include <hip/hip_bf16.h>
#include <math.h>

// ---- static problem config ----
// B=24, H=W=60, DIM=256, NH=8, HD=32, WS=7, SS=3, N=49, HP=WP=63, NW=81
// rows_att = 24*81*49 = 95256 ; rows_mlp = 24*3600 = 86400

typedef _Float16 half8 __attribute__((ext_vector_type(8)));
typedef _Float16 half4_t __attribute__((ext_vector_type(4)));
typedef float f32x4 __attribute__((ext_vector_type(4)));

// async global->LDS, 16B per lane. LDS dest = uniform base + lane*16.
#define GLDS16(gp, lp)                                                    \
  __builtin_amdgcn_global_load_lds(                                      \
      (__attribute__((address_space(1))) const void*)(gp),               \
      (__attribute__((address_space(3))) void*)(lp), 16, 0, 0)

// LDS-only barrier: wait own ds ops, then raw s_barrier. Unlike __syncthreads
// this does NOT drain vmcnt -> global loads stay in flight across the barrier.
#define LGKM_BARRIER()                                                    \
  do {                                                                    \
    asm volatile("s_waitcnt lgkmcnt(0)" ::: "memory");                    \
    __builtin_amdgcn_s_barrier();                                         \
  } while (0)

__device__ __forceinline__ float wave_reduce_sum(float v) {
  v += __shfl_xor(v, 1);
  v += __shfl_xor(v, 2);
  v += __shfl_xor(v, 4);
  v += __shfl_xor(v, 8);
  v += __shfl_xor(v, 16);
  v += __shfl_xor(v, 32);
  return v;
}

// ---------------- weight transpose + f16 convert (Bt layout: N x K) -----------
__global__ __launch_bounds__(256) void prep_weights(
    const float* __restrict__ wqkv, const float* __restrict__ wproj,
    const float* __restrict__ wfc1, const float* __restrict__ wfc2,
    _Float16* __restrict__ oqkv, _Float16* __restrict__ oproj,
    _Float16* __restrict__ ofc1, _Float16* __restrict__ ofc2)
{
  int idx = blockIdx.x * 256 + threadIdx.x;
  if (idx < 196608) {                       // w_qkv: 256x768 -> 768x256
    int n = idx / 256, k = idx % 256;
    oqkv[idx] = (_Float16)wqkv[k * 768 + n];
  } else if (idx < 262144) {                // w_proj: 256x256 -> 256x256
    int i = idx - 196608; int n = i / 256, k = i % 256;
    oproj[i] = (_Float16)wproj[k * 256 + n];
  } else if (idx < 524288) {                // w_fc1: 256x1024 -> 1024x256
    int i = idx - 262144; int n = i / 256, k = i % 256;
    ofc1[i] = (_Float16)wfc1[k * 1024 + n];
  } else {                                  // w_fc2: 1024x256 -> 256x1024
    int i = idx - 524288; int n = i / 1024, k = i % 1024;
    ofc2[i] = (_Float16)wfc2[k * 256 + n];
  }
}

// ------- combined rel-bias + shift-mask table: CB[class][head][64][64] f16 ----
// class c: bit1 = (wh==8), bit0 = (ww==8). Pad rows/cols get -60000 (softmax 0).
__global__ __launch_bounds__(256) void prep_cb(
    const float* __restrict__ rbt, _Float16* __restrict__ cbt)
{
  int idx = blockIdx.x * 256 + threadIdx.x;   // 4*8*64*64 = 131072
  int m = idx & 63, n = (idx >> 6) & 63;
  int hc = idx >> 12; int h = hc & 7, c = hc >> 3;
  float v;
  if (n < 49 && m < 49) {
    int i1 = n / 7, j1 = n % 7, i2 = m / 7, j2 = m % 7;
    float bias = rbt[((i1 - i2 + 6) * 13 + (j1 - j2 + 6)) * 8 + h];
    int rh1 = (c & 2) ? (i1 < 4 ? 1 : 2) : 0;
    int rh2 = (c & 2) ? (i2 < 4 ? 1 : 2) : 0;
    int rw1 = (c & 1) ? (j1 < 4 ? 1 : 2) : 0;
    int rw2 = (c & 1) ? (j2 < 4 ? 1 : 2) : 0;
    v = bias + (((rh1 != rh2) || (rw1 != rw2)) ? -100.f : 0.f);
  } else {
    v = -60000.f;
  }
  cbt[idx] = (_Float16)v;
}

// --------- LN1 fused with pad + cyclic shift(-3,-3) + window partition --------
__global__ __launch_bounds__(256) void ln1_window_kernel(
    const float* __restrict__ x, const float* __restrict__ g,
    const float* __restrict__ bta, _Float16* __restrict__ xw,
    int row0, int rows_c)
{
  int lrow = blockIdx.x * 4 + (threadIdx.x >> 6);
  if (lrow >= rows_c) return;               // whole wave exits together
  int row = row0 + lrow;
  int lane = threadIdx.x & 63;
  int bw = row / 49, n = row - bw * 49;
  int b = bw / 81, win = bw - b * 81;
  int wh = win / 9, ww = win - wh * 9;
  int i = n / 7, j = n - i * 7;
  int sh = wh * 7 + i + 3; if (sh >= 63) sh -= 63;
  int sw = ww * 7 + j + 3; if (sw >= 63) sw -= 63;
  bool valid = (sh < 60) && (sw < 60);
  float4 v = make_float4(0.f, 0.f, 0.f, 0.f);
  if (valid)
    v = reinterpret_cast<const float4*>(x + ((size_t)b * 3600 + sh * 60 + sw) * 256)[lane];
  float s = v.x + v.y + v.z + v.w;
  s = wave_reduce_sum(s);
  float mu = s * (1.f / 256.f);
  float dx = v.x - mu, dy = v.y - mu, dz = v.z - mu, dw = v.w - mu;
  float q = dx * dx + dy * dy + dz * dz + dw * dw;
  q = wave_reduce_sum(q);
  float rs = rsqrtf(q * (1.f / 256.f) + 1e-5f);
  float4 gv = reinterpret_cast<const float4*>(g)[lane];
  float4 bv = reinterpret_cast<const float4*>(bta)[lane];
  union { _Float16 h[4]; uint2 u; } pk;
  if (valid) {
    pk.h[0] = (_Float16)(dx * rs * gv.x + bv.x);
    pk.h[1] = (_Float16)(dy * rs * gv.y + bv.y);
    pk.h[2] = (_Float16)(dz * rs * gv.z + bv.z);
    pk.h[3] = (_Float16)(dw * rs * gv.w + bv.w);
  } else {
    pk.h[0] = pk.h[1] = pk.h[2] = pk.h[3] = (_Float16)0.f;
  }
  *reinterpret_cast<uint2*>(xw + (size_t)lrow * 256 + lane * 4) = pk.u;
}

// --------------------------- MFMA f16 GEMM (Bt input) -------------------------
// C[M,N] = A[M,K] * Bt[N,K]^T + bias. 128x128 tile, 4 waves, 4x4 16x16x32
// frags with SWAPPED operands (mfma(b,a)): each lane's f32x4 acc = 4 consecutive
// output columns of one row -> register-direct vectorized epilogue.
// BK=64, double-buffered LDS, global_load_lds width-16 staging.
__global__ __launch_bounds__(256, 2) void gemm_kernel(
    const _Float16* __restrict__ A, const _Float16* __restrict__ Bt,
    const float* __restrict__ bias, const float* __restrict__ resid,
    void* __restrict__ out, int M, int N, int K, int mode, int row0)
{
  __shared__ __align__(16) _Float16 lds[2][2][8192];  // [buf][A/B][128*64]
  const int tid = threadIdx.x;
  const int n0 = blockIdx.x * 128, m0 = blockIdx.y * 128;
  const int wv = tid >> 6, ln = tid & 63;
  const int wm = (wv >> 1) * 64, wn = (wv & 1) * 64;
  const int quad = ln >> 4, l16 = ln & 15;

  const int rl = ln >> 3;                 // row within slot
  const int gseg = ((ln & 7) ^ rl) << 3;  // swizzled 16B segment (f16 units)
  const _Float16* gA[4]; const _Float16* gB[4];
#pragma unroll
  for (int s = 0; s < 4; s++) {
    int r = wv * 32 + s * 8 + rl;
    int gm = m0 + r; if (gm >= M) gm = M - 1;   // clamp: dup rows, epi-skipped
    gA[s] = A + (size_t)gm * K + gseg;
    gB[s] = Bt + (size_t)(n0 + r) * K + gseg;
  }

  int offA[2][4], offB[2][4];
#pragma unroll
  for (int i = 0; i < 4; i++) {
    int ra = wm + i * 16 + l16;
    int rb = wn + i * 16 + l16;
    int sw0 = l16 & 7;
#pragma unroll
    for (int ks = 0; ks < 2; ks++) {
      offA[ks][i] = ra * 64 + (((ks * 4 + quad) ^ sw0) << 3);
      offB[ks][i] = rb * 64 + (((ks * 4 + quad) ^ sw0) << 3);
    }
  }

  f32x4 acc[4][4];
#pragma unroll
  for (int i = 0; i < 4; i++)
#pragma unroll
    for (int j = 0; j < 4; j++) acc[i][j] = (f32x4)0.f;

#define STAGE(buf, koff)                                                   \
  {                                                                        \
    _Float16* la = &lds[buf][0][wv * 2048];                                \
    _Float16* lb = &lds[buf][1][wv * 2048];                                \
    GLDS16(gA[0] + (koff), la);        GLDS16(gB[0] + (koff), lb);         \
    GLDS16(gA[1] + (koff), la + 512);  GLDS16(gB[1] + (koff), lb + 512);   \
    GLDS16(gA[2] + (koff), la + 1024); GLDS16(gB[2] + (koff), lb + 1024);  \
    GLDS16(gA[3] + (koff), la + 1536); GLDS16(gB[3] + (koff), lb + 1536);  \
  }

  const int nt = K >> 6;
  STAGE(0, 0);
  __syncthreads();
  for (int t = 0; t < nt; t++) {
    const int cur = t & 1;
    half8 a0[4], b0[4], a1[4], b1[4];
#pragma unroll
    for (int i = 0; i < 4; i++) {
      a0[i] = *reinterpret_cast<const half8*>(&lds[cur][0][offA[0][i]]);
      a1[i] = *reinterpret_cast<const half8*>(&lds[cur][0][offA[1][i]]);
      b0[i] = *reinterpret_cast<const half8*>(&lds[cur][1][offB[0][i]]);
      b1[i] = *reinterpret_cast<const half8*>(&lds[cur][1][offB[1][i]]);
    }
    if (t + 1 < nt) STAGE(cur ^ 1, (t + 1) << 6);
#pragma unroll
    for (int i = 0; i < 4; i++)
#pragma unroll
      for (int j = 0; j < 4; j++)
        acc[i][j] = __builtin_amdgcn_mfma_f32_16x16x32_f16(b0[j], a0[i], acc[i][j], 0, 0, 0);
#pragma unroll
    for (int i = 0; i < 4; i++)
#pragma unroll
      for (int j = 0; j < 4; j++)
        acc[i][j] = __builtin_amdgcn_mfma_f32_16x16x32_f16(b1[j], a1[i], acc[i][j], 0, 0, 0);
    __syncthreads();
  }
#undef STAGE

  f32x4 bias4[4];
#pragma unroll
  for (int j = 0; j < 4; j++)
    bias4[j] = *reinterpret_cast<const f32x4*>(bias + n0 + wn + j * 16 + quad * 4);

#pragma unroll
  for (int i = 0; i < 4; i++) {
    int gm = m0 + wm + i * 16 + l16;
    if (gm >= M) continue;
    if (mode == 0) {               // qkv: f16 out, scale q columns
      _Float16* op = reinterpret_cast<_Float16*>(out) + (size_t)gm * N + n0 + wn;
#pragma unroll
      for (int j = 0; j < 4; j++) {
        float sc = (n0 + wn + j * 16) < 256 ? 0.17677669529663687f : 1.f;
        half4_t o4;
#pragma unroll
        for (int r = 0; r < 4; r++)
          o4[r] = (_Float16)((acc[i][j][r] + bias4[j][r]) * sc);
        *reinterpret_cast<half4_t*>(op + j * 16 + quad * 4) = o4;
      }
    } else {                       // mode 1: reverse window+shift+unpad+resid
      int gmg = gm + row0;
      int bw = gmg / 49, nn = gmg - bw * 49;
      int bidx = bw / 81, win = bw - bidx * 81;
      int wh = win / 9, wwn = win - wh * 9;
      int ii = nn / 7, jj = nn - ii * 7;
      int sh = wh * 7 + ii + 3; if (sh >= 63) sh -= 63;
      int sw = wwn * 7 + jj + 3; if (sw >= 63) sw -= 63;
      if (sh < 60 && sw < 60) {
        size_t o = ((size_t)bidx * 3600 + sh * 60 + sw) * 256 + n0 + wn;
        float* op = reinterpret_cast<float*>(out) + o;
        const float* rp = resid + o;
#pragma unroll
        for (int j = 0; j < 4; j++) {
          f32x4 rv = *reinterpret_cast<const f32x4*>(rp + j * 16 + quad * 4);
          f32x4 v = acc[i][j] + bias4[j] + rv;
          *reinterpret_cast<f32x4*>(op + j * 16 + quad * 4) = v;
        }
      }
    }
  }
}

// -------------- fused MLP: LN2 + FC1 + GELU + FC2 + residual ------------------
// R7 geometry (64 rows, 4 col-split waves, A 32KB + H dbuf 2x16KB). R8 change:
// all __syncthreads -> LGKM_BARRIER (raw s_barrier + lgkmcnt-only wait). This
// removes the vmcnt(0) drain __syncthreads implies, so the batched W1/W2 global
// loads and the X/acc preload genuinely stay in flight across barriers.
// + LN2 depth-2 load pipeline, + setprio around MFMA clusters (T5).
__global__ __launch_bounds__(256, 2) void fused_mlp_kernel(
    const float* __restrict__ X, const _Float16* __restrict__ W1t,
    const float* __restrict__ B1v, const _Float16* __restrict__ W2t,
    const float* __restrict__ B2v, const float* __restrict__ g,
    const float* __restrict__ bt, float* __restrict__ out, int M)
{
  __shared__ __align__(16) _Float16 Alds[64 * 256];     // 32 KB
  __shared__ __align__(16) _Float16 Hlds[2][64 * 128];  // 2 x 16 KB
  const int tid = threadIdx.x;
  const int wv = tid >> 6, ln = tid & 63;
  const int quad = ln >> 4, l16 = ln & 15;
  const int m0 = blockIdx.x * 64;
  const int wn1 = wv * 32;     // GEMM1 col base (128-wide chunk)
  const int wn2 = wv * 64;     // GEMM2 col base (256-wide out)

  // ---- LN2: wave wv normalizes rows [wv*16, wv*16+16) into Alds (pipelined) --
  {
    float4 gv = reinterpret_cast<const float4*>(g)[ln];
    float4 bv = reinterpret_cast<const float4*>(bt)[ln];
    const int seg = ln >> 1;    // 16B segment within row (32/row)
    int gr = m0 + wv * 16; if (gr >= M) gr = M - 1;
    float4 xv = reinterpret_cast<const float4*>(X + (size_t)gr * 256)[ln];
    for (int rr = 0; rr < 16; rr++) {
      float4 nxt;
      if (rr < 15) {
        int gn = m0 + wv * 16 + rr + 1; if (gn >= M) gn = M - 1;
        nxt = reinterpret_cast<const float4*>(X + (size_t)gn * 256)[ln];
      }
      float s = wave_reduce_sum(xv.x + xv.y + xv.z + xv.w);
      float mu = s * (1.f / 256.f);
      float dx = xv.x - mu, dy = xv.y - mu, dz = xv.z - mu, dw = xv.w - mu;
      float q = wave_reduce_sum(dx * dx + dy * dy + dz * dz + dw * dw);
      float rs = rsqrtf(q * (1.f / 256.f) + 1e-5f);
      union { _Float16 h[4]; uint2 u; } pk;
      pk.h[0] = (_Float16)(dx * rs * gv.x + bv.x);
      pk.h[1] = (_Float16)(dy * rs * gv.y + bv.y);
      pk.h[2] = (_Float16)(dz * rs * gv.z + bv.z);
      pk.h[3] = (_Float16)(dw * rs * gv.w + bv.w);
      int lr = wv * 16 + rr;
      *reinterpret_cast<uint2*>(
          &Alds[lr * 256 + ((seg ^ (lr & 31)) << 3) + (ln & 1) * 4]) = pk.u;
      xv = nxt;
    }
  }

  // ---- preload acc = X + b_fc2 (residual + bias folded) ----
  // Issued before the barrier; raw barrier leaves these loads in flight until
  // first use (chunk 0 GEMM2) -> latency hidden under LN2-barrier + GEMM1.
  f32x4 acc[4][4];
  {
    f32x4 b2q[4];
#pragma unroll
    for (int j = 0; j < 4; j++)
      b2q[j] = *reinterpret_cast<const f32x4*>(B2v + wn2 + j * 16 + quad * 4);
#pragma unroll
    for (int i = 0; i < 4; i++) {
      int gr = m0 + i * 16 + l16; if (gr >= M) gr = M - 1;
      const float* xp = X + (size_t)gr * 256 + wn2;
#pragma unroll
      for (int j = 0; j < 4; j++)
        acc[i][j] = *reinterpret_cast<const f32x4*>(xp + j * 16 + quad * 4) + b2q[j];
    }
  }
  LGKM_BARRIER();   // Alds visible; global loads NOT drained

  for (int n1c = 0; n1c < 8; n1c++) {
    // ---- batch-load ALL W1 fragments for this chunk (16 loads in flight) ----
    const _Float16* w1p = W1t + (size_t)(n1c * 128 + wn1) * 256;
    half8 w1f[8][2];
#pragma unroll
    for (int st = 0; st < 8; st++)
#pragma unroll
      for (int j = 0; j < 2; j++)
        w1f[st][j] = *reinterpret_cast<const half8*>(
            w1p + (size_t)(j * 16 + l16) * 256 + st * 32 + quad * 8);

    // ---- GEMM1: acch[64 x 32(wave)] = A x W1t[chunk]^T ----
    f32x4 acch[4][2];
#pragma unroll
    for (int i = 0; i < 4; i++)
#pragma unroll
      for (int j = 0; j < 2; j++) acch[i][j] = (f32x4)0.f;
    __builtin_amdgcn_s_setprio(1);
#pragma unroll
    for (int st = 0; st < 8; st++) {
      half8 af[4];
#pragma unroll
      for (int i = 0; i < 4; i++) {
        int ra = i * 16 + l16;
        af[i] = *reinterpret_cast<const half8*>(
            &Alds[ra * 256 + (((st * 4 + quad) ^ (ra & 31)) << 3)]);
      }
#pragma unroll
      for (int i = 0; i < 4; i++)
#pragma unroll
        for (int j = 0; j < 2; j++)
          acch[i][j] = __builtin_amdgcn_mfma_f32_16x16x32_f16(w1f[st][j], af[i], acch[i][j], 0, 0, 0);
    }
    __builtin_amdgcn_s_setprio(0);

    // ---- batch-issue ALL W2 fragments: latency hides under GELU + barrier ----
    const _Float16* w2p = W2t + (size_t)wn2 * 1024 + n1c * 128;
    half8 w2f[4][4];
#pragma unroll
    for (int p = 0; p < 4; p++)
#pragma unroll
      for (int j = 0; j < 4; j++)
        w2f[p][j] = *reinterpret_cast<const half8*>(
            w2p + (size_t)(j * 16 + l16) * 1024 + p * 32 + quad * 8);

    // ---- bias + GELU -> Hlds[n1c&1] (f16, swizzled) ----
    _Float16* hb = &Hlds[n1c & 1][0];
    {
      f32x4 b1q[2];
#pragma unroll
      for (int j = 0; j < 2; j++)
        b1q[j] = *reinterpret_cast<const f32x4*>(B1v + n1c * 128 + wn1 + j * 16 + quad * 4);
#pragma unroll
      for (int i = 0; i < 4; i++) {
        int m = i * 16 + l16;
#pragma unroll
        for (int j = 0; j < 2; j++) {
          int n = wn1 + j * 16 + quad * 4;
          half4_t o4;
#pragma unroll
          for (int r = 0; r < 4; r++) {
            float v = acch[i][j][r] + b1q[j][r];
            v = 0.5f * v * (1.f + erff(v * 0.70710678118654752f));
            o4[r] = (_Float16)v;
          }
          *reinterpret_cast<half4_t*>(
              &hb[m * 128 + (((n >> 3) ^ (m & 15)) << 3) + (quad & 1) * 4]) = o4;
        }
      }
    }
    LGKM_BARRIER();   // H[buf] visible; W loads stay in flight
    // WAR on Hlds[buf]: next write of this buf is 2 chunks away, separated by
    // two barriers, and each wave's reads complete before it reaches a barrier
    // (compiler lgkmcnt waits precede the consuming MFMAs). Same as R7 proof.

    // ---- GEMM2: acc += H x W2t[:, chunk]^T (w2f resident by now) ----
    __builtin_amdgcn_s_setprio(1);
#pragma unroll
    for (int p = 0; p < 4; p++) {
      half8 hf[4];
#pragma unroll
      for (int i = 0; i < 4; i++) {
        int mh = i * 16 + l16;
        hf[i] = *reinterpret_cast<const half8*>(
            &hb[mh * 128 + (((p * 4 + quad) ^ (mh & 15)) << 3)]);
      }
#pragma unroll
      for (int i = 0; i < 4; i++)
#pragma unroll
        for (int j = 0; j < 4; j++)
          acc[i][j] = __builtin_amdgcn_mfma_f32_16x16x32_f16(w2f[p][j], hf[i], acc[i][j], 0, 0, 0);
    }
    __builtin_amdgcn_s_setprio(0);
  }

  // ---- store out (fp32, in-place over X rows) ----
#pragma unroll
  for (int i = 0; i < 4; i++) {
    int gm = m0 + i * 16 + l16;
    if (gm >= M) continue;
    float* op = out + (size_t)gm * 256 + wn2;
#pragma unroll
    for (int j = 0; j < 4; j++)
      *reinterpret_cast<f32x4*>(op + j * 16 + quad * 4) = acc[i][j];
  }
}

// ------------------------ MFMA windowed attention -----------------------------
__global__ __launch_bounds__(64) void attn_mfma(
    const _Float16* __restrict__ qkv, const _Float16* __restrict__ cbt,
    _Float16* __restrict__ outp)
{
  __shared__ __align__(16) _Float16 VT[32][72];   // V^T[d][m], m 49..63 zeroed
  __shared__ __align__(16) _Float16 Ps[64][72];   // P[n][m]
  const int bwh = blockIdx.x;
  const int bw = bwh >> 3, h = bwh & 7;
  const int win = bw % 81;
  const int wh = win / 9, ww = win - wh * 9;
  const int cls = ((wh == 8) ? 2 : 0) | ((ww == 8) ? 1 : 0);
  const int lane = threadIdx.x;
  const int quad = lane >> 4, l16 = lane & 15;

  for (int e = lane; e < 480; e += 64) {          // zero pad cols m=49..63
    int d = e / 15, m = 49 + e % 15;
    VT[d][m] = (_Float16)0.f;
  }
  const size_t vbase = (size_t)bw * 49 * 768 + 512 + h * 32;
  for (int e = lane; e < 1568; e += 64) {
    int m = e >> 5, d = e & 31;
    VT[d][m] = qkv[vbase + (size_t)m * 768 + d];
  }

  const _Float16* qb = qkv + (size_t)bw * 49 * 768 + h * 32 + quad * 8;
  half8 kf[4], qf[4];
  const half8 hz = (half8)(_Float16)0.f;
#pragma unroll
  for (int t = 0; t < 4; t++) {
    int row = t * 16 + l16;
    int rc = row < 49 ? row : 48;
    half8 kv = *reinterpret_cast<const half8*>(qb + 256 + (size_t)rc * 768);
    half8 qv = *reinterpret_cast<const half8*>(qb + (size_t)rc * 768);
    kf[t] = row < 49 ? kv : hz;
    qf[t] = row < 49 ? qv : hz;
  }

  f32x4 S[4][4];
#pragma unroll
  for (int mt = 0; mt < 4; mt++)
#pragma unroll
    for (int nt = 0; nt < 4; nt++) S[mt][nt] = (f32x4)0.f;
#pragma unroll
  for (int mt = 0; mt < 4; mt++)
#pragma unroll
    for (int nt = 0; nt < 4; nt++)
      S[mt][nt] = __builtin_amdgcn_mfma_f32_16x16x32_f16(kf[mt], qf[nt], S[mt][nt], 0, 0, 0);

  const _Float16* cbp = cbt + (((size_t)cls * 8 + h) << 12);
#pragma unroll
  for (int nt = 0; nt < 4; nt++) {
    int n = nt * 16 + l16;
#pragma unroll
    for (int mt = 0; mt < 4; mt++) {
      half4_t cb4 = *reinterpret_cast<const half4_t*>(cbp + n * 64 + mt * 16 + quad * 4);
#pragma unroll
      for (int r = 0; r < 4; r++) S[mt][nt][r] += (float)cb4[r];
    }
  }

  float inv[4];
#pragma unroll
  for (int nt = 0; nt < 4; nt++) {
    float mx = -3.0e38f;
#pragma unroll
    for (int mt = 0; mt < 4; mt++)
#pragma unroll
      for (int r = 0; r < 4; r++) mx = fmaxf(mx, S[mt][nt][r]);
    mx = fmaxf(mx, __shfl_xor(mx, 16));
    mx = fmaxf(mx, __shfl_xor(mx, 32));
    float sm = 0.f;
#pragma unroll
    for (int mt = 0; mt < 4; mt++)
#pragma unroll
      for (int r = 0; r < 4; r++) {
        float e = __expf(S[mt][nt][r] - mx);
        S[mt][nt][r] = e;
        sm += e;
      }
    sm += __shfl_xor(sm, 16);
    sm += __shfl_xor(sm, 32);
    inv[nt] = 1.f / sm;
  }

#pragma unroll
  for (int nt = 0; nt < 4; nt++) {
#pragma unroll
    for (int mt = 0; mt < 4; mt++) {
      half4_t p;
#pragma unroll
      for (int r = 0; r < 4; r++) p[r] = (_Float16)(S[mt][nt][r] * inv[nt]);
      *reinterpret_cast<half4_t*>(&Ps[nt * 16 + l16][mt * 16 + quad * 4]) = p;
    }
  }
  __syncthreads();

  f32x4 O[2][4];
#pragma unroll
  for (int dt = 0; dt < 2; dt++)
#pragma unroll
    for (int nt = 0; nt < 4; nt++) O[dt][nt] = (f32x4)0.f;
#pragma unroll
  for (int ks = 0; ks < 2; ks++) {
    half8 va[2], pb[4];
#pragma unroll
    for (int dt = 0; dt < 2; dt++)
      va[dt] = *reinterpret_cast<const half8*>(&VT[dt * 16 + l16][ks * 32 + quad * 8]);
#pragma unroll
    for (int nt = 0; nt < 4; nt++)
      pb[nt] = *reinterpret_cast<const half8*>(&Ps[nt * 16 + l16][ks * 32 + quad * 8]);
#pragma unroll
    for (int dt = 0; dt < 2; dt++)
#pragma unroll
      for (int nt = 0; nt < 4; nt++)
        O[dt][nt] = __builtin_amdgcn_mfma_f32_16x16x32_f16(va[dt], pb[nt], O[dt][nt], 0, 0, 0);
  }

#pragma unroll
  for (int nt = 0; nt < 4; nt++) {
    int n = nt * 16 + l16;
    if (n < 49) {
#pragma unroll
      for (int dt = 0; dt < 2; dt++) {
        half4_t o4;
#pragma unroll
        for (int r = 0; r < 4; r++) o4[r] = (_Float16)O[dt][nt][r];
        *reinterpret_cast<half4_t*>(
            outp + ((size_t)bw * 49 + n) * 256 + h * 32 + dt * 16 + quad * 4) = o4;
      }
    }
  }
}

// --------------------------------- launcher -----------------------------------
extern "C" void kernel_launch(void* const* d_in, const int* in_sizes, int n_in,
                              void* d_out, int out_size, void* d_ws, size_t ws_size,
                              hipStream_t stream) {
  const float* x      = (const float*)d_in[0];
  const float* g1     = (const float*)d_in[1];
  const float* b1     = (const float*)d_in[2];
  const float* w_qkv  = (const float*)d_in[3];
  const float* b_qkv  = (const float*)d_in[4];
  const float* rbt    = (const float*)d_in[5];
  const float* w_proj = (const float*)d_in[6];
  const float* b_proj = (const float*)d_in[7];
  const float* g2     = (const float*)d_in[8];
  const float* b2     = (const float*)d_in[9];
  const float* w_fc1  = (const float*)d_in[10];
  const float* b_fc1  = (const float*)d_in[11];
  const float* w_fc2  = (const float*)d_in[12];
  const float* b_fc2  = (const float*)d_in[13];
  float* outp = (float*)d_out;   // doubles as the x2 residual buffer

  // weights (persistent): 1.5 MB transposed f16 + 256 KB CB table
  char* ws = (char*)d_ws;
  _Float16* wqkvT  = (_Float16*)(ws + 0);          // 768*256*2  = 393216
  _Float16* wprojT = (_Float16*)(ws + 393216);     // 256*256*2  = 131072
  _Float16* wfc1T  = (_Float16*)(ws + 524288);     // 1024*256*2 = 524288
  _Float16* wfc2T  = (_Float16*)(ws + 1048576);    // 256*1024*2 = 524288
  _Float16* cbt    = (_Float16*)(ws + 1572864);    // 4*8*64*64*2 = 262144
  const size_t WB = 1835008;

  // chunk size: largest cb (batches per chunk) whose scratch fits ws_size.
  // region1 (xw/attn_out): cb*3969*256*2 = cb*2032128
  // region2 (qkv):         cb*3969*768*2 = cb*6096384
  const int cand[8] = {24, 12, 8, 6, 4, 3, 2, 1};
  int cb = 1;
  for (int ci = 0; ci < 8; ci++) {
    size_t need = WB + (size_t)cand[ci] * (2032128u + 6096384u);
    if (ws_size >= need) { cb = cand[ci]; break; }
  }
  const int nch = 24 / cb;

  _Float16* r1 = (_Float16*)(ws + WB);                               // xw / attn_out
  _Float16* r2 = (_Float16*)(ws + WB + (size_t)cb * 2032128u);       // qkv

  prep_weights<<<3072, 256, 0, stream>>>(w_qkv, w_proj, w_fc1, w_fc2,
                                         wqkvT, wprojT, wfc1T, wfc2T);
  prep_cb<<<512, 256, 0, stream>>>(rbt, cbt);

  for (int c = 0; c < nch; c++) {
    const int b0 = c * cb;
    const int rows_att = cb * 81 * 49;      // 3969*cb
    const int row0_att = b0 * 81 * 49;
    const int rows_mlp = cb * 3600;
    const int row0_mlp = b0 * 3600;

    // LN1 + shift + pad + window partition -> r1 (f16)
    ln1_window_kernel<<<(rows_att + 3) / 4, 256, 0, stream>>>(
        x, g1, b1, r1, row0_att, rows_att);
    // QKV GEMM -> r2 (f16), q pre-scaled  (grid: x = n-blocks for L2 A-reuse)
    {
      dim3 g(6, (rows_att + 127) / 128);
      gemm_kernel<<<g, 256, 0, stream>>>(r1, wqkvT, b_qkv, nullptr, r2,
                                         rows_att, 768, 256, 0, 0);
    }
    // MFMA windowed attention -> r1 (f16) (r1's xw is dead)
    attn_mfma<<<cb * 81 * 8, 64, 0, stream>>>(r2, cbt, r1);
    // proj GEMM + reverse-window scatter + residual -> d_out (fp32)
    {
      dim3 g(2, (rows_att + 127) / 128);
      gemm_kernel<<<g, 256, 0, stream>>>(r1, wprojT, b_proj, x, outp,
                                         rows_att, 256, 256, 1, row0_att);
    }
    // fused LN2 + FC1 + GELU + FC2 + residual (in-place on d_out)
    {
      float* od = outp + (size_t)row0_mlp * 256;
      fused_mlp_kernel<<<(rows_mlp + 63) / 64, 256, 0, stream>>>(
          od, wfc1T, b_fc1, wfc2T, b_fc2, g2, b2, od, rows_mlp);
    }
  }
}